// Round 6
// baseline (511.239 us; speedup 1.0000x reference)
//
#include <hip/hip_runtime.h>
#include <hip/hip_cooperative_groups.h>

namespace cg = cooperative_groups;

// Problem: x (B=4, C=256, D=32, H=64, W=64) fp32.
// 1) reflect-pad(2) + per-(b,c) mean  == weighted sum over original x
// 2) LSTMCell scan over C=256 channels (B=4, hidden=32, input=1)
// 3) gate[b,c] = sigmoid(h_c . gate_w + gate_b);  out = x * gate[b,c]
// Single cooperative kernel (512 blocks, 2 channels each), grid.sync between
// phases; deterministic 3-launch fallback if cooperative launch is refused.

#define CH_F4 32768          // 131072 floats per (b,c) channel = 32768 float4
#define GRID 512             // 2 blocks/CU needed; LDS allows 4, VGPR >= 2
#define MEAN_DEN (1.0f / 166464.0f)   // 36*68*68

typedef unsigned int uint;
typedef float f32x4 __attribute__((ext_vector_type(4)));

__device__ __forceinline__ float sigf(float x) {
    return 1.0f / (1.0f + __expf(-x));
}
__device__ __forceinline__ float tanh_fast(float x) {
    return fmaf(2.0f, sigf(2.0f * x), -1.0f);   // tanh(x) = 2*sigmoid(2x) - 1
}

__global__ __launch_bounds__(256) void fused_kernel(
    const float* __restrict__ x,
    const float* __restrict__ W_ih, const float* __restrict__ W_hh,
    const float* __restrict__ b_ih, const float* __restrict__ b_hh,
    const float* __restrict__ gate_w, const float* __restrict__ gate_b,
    float* __restrict__ out, float* __restrict__ ws, int phase_mask)
{
    float* __restrict__ cseq  = ws;          // 1024 floats
    float* __restrict__ gates = ws + 1024;   // 1024 floats

    __shared__ float red[256];               // phase1 reduce; phase2 reuses as cs[]
    __shared__ float hist[257 * 33];         // phase2 h history (stride-33)

    const int bc  = blockIdx.x;              // channel pair: bc and bc+512
    const int tid = threadIdx.x;

    // ---------- phase 1: weighted channel means (reflect-pad mean) ----------
    if (phase_mask & 1) {
        const f32x4* __restrict__ p0 = (const f32x4*)x + (size_t)bc * CH_F4;
        const f32x4* __restrict__ p1 = p0 + (size_t)GRID * CH_F4;
        float s0 = 0.0f, s1 = 0.0f;
        for (int i = tid; i < CH_F4; i += 256) {
            f32x4 v0 = p0[i];
            f32x4 v1 = p1[i];
            const int q = i & 15;            // float4 index within W-row
            const int h = (i >> 4) & 63;
            const int d = i >> 10;
            const float wd = ((d == 1) | (d == 2) | (d == 29) | (d == 30)) ? 2.0f : 1.0f;
            const float wh = ((h == 1) | (h == 2) | (h == 61) | (h == 62)) ? 2.0f : 1.0f;
            const float w = wd * wh;
            float t0 = (v0.x + v0.y) + (v0.z + v0.w);
            float t1 = (v1.x + v1.y) + (v1.z + v1.w);
            if (q == 0 || q == 15) {         // W positions 1,2,61,62 doubled
                t0 += v0.y + v0.z;
                t1 += v1.y + v1.z;
            }
            s0 = fmaf(w, t0, s0);
            s1 = fmaf(w, t1, s1);
        }
        red[tid] = s0;
        __syncthreads();
        for (int s = 128; s > 0; s >>= 1) {
            if (tid < s) red[tid] += red[tid + s];
            __syncthreads();
        }
        if (tid == 0) cseq[bc] = red[0] * MEAN_DEN;
        __syncthreads();
        red[tid] = s1;
        __syncthreads();
        for (int s = 128; s > 0; s >>= 1) {
            if (tid < s) red[tid] += red[tid + s];
            __syncthreads();
        }
        if (tid == 0) cseq[bc + GRID] = red[0] * MEAN_DEN;
        __syncthreads();
    }
    if (phase_mask == 7) cg::this_grid().sync();

    // ---------- phase 2: LSTM scan, blocks 0..3, wave 0 only, barrier-free ----------
    // Lane l owns gate rows l and l+64 (l<32: i,g ; l>=32: f,o). h register-resident
    // (lane k holds h_k); broadcast via v_readlane; i/f<->g/o via permlane32_swap.
    // Single-wave LDS comms (cs, hist): same-wave DS ops are ordered, no barrier.
    if ((phase_mask & 2) && bc < 4 && tid < 64) {
        const int b = bc, l = tid;
        float* cs = red;                     // 256 channel means for this batch

        const float wih0 = W_ih[l];
        const float wih1 = W_ih[l + 64];
        const float bias0 = b_ih[l] + b_hh[l];
        const float bias1 = b_ih[l + 64] + b_hh[l + 64];
        float whh0[32], whh1[32];
#pragma unroll
        for (int k = 0; k < 32; k++) {
            whh0[k] = W_hh[l * 32 + k];
            whh1[k] = W_hh[(l + 64) * 32 + k];
        }
#pragma unroll
        for (int i = 0; i < 4; i++) cs[i * 64 + l] = cseq[b * 256 + i * 64 + l];
        float h = 0.0f, c = 0.0f;

        for (int t = 0; t < 256; t++) {
            const float inp = cs[t];
            float z0 = fmaf(inp, wih0, bias0);
            float z1 = fmaf(inp, wih1, bias1);
#pragma unroll
            for (int k = 0; k < 32; k++) {
                const float hk = __builtin_bit_cast(float,
                    __builtin_amdgcn_readlane(__builtin_bit_cast(int, h), k));
                z0 = fmaf(hk, whh0[k], z0);
                z1 = fmaf(hk, whh1[k], z1);
            }
            float zf, zo;
#if __has_builtin(__builtin_amdgcn_permlane32_swap)
            {
                auto ra = __builtin_amdgcn_permlane32_swap(
                    __builtin_bit_cast(uint, z0), __builtin_bit_cast(uint, z0), false, false);
                auto rb = __builtin_amdgcn_permlane32_swap(
                    __builtin_bit_cast(uint, z1), __builtin_bit_cast(uint, z1), false, false);
                zf = __builtin_bit_cast(float, ra[1]);
                zo = __builtin_bit_cast(float, rb[1]);
            }
#else
            zf = __shfl_xor(z0, 32);
            zo = __shfl_xor(z1, 32);
#endif
            // valid in lanes<32 only (high lanes compute finite garbage, never read)
            c = sigf(zf) * c + sigf(z0) * tanh_fast(z1);
            h = sigf(zo) * tanh_fast(c);
            if (l < 32) hist[(t + 1) * 33 + l] = h;   // off critical path
        }

        // deferred output gates: lane handles t = l, l+64, l+128, l+192.
        // gate_w read via uniform s_loads (k compile-time) - no VGPR array.
        const float gb = gate_b[0];
#pragma unroll
        for (int chunk = 0; chunk < 4; chunk++) {
            const int t = chunk * 64 + l;
            const float* hrow = &hist[(t + 1) * 33];
            float s = gb;
#pragma unroll
            for (int k = 0; k < 32; k++) s = fmaf(hrow[k], gate_w[k], s);
            gates[b * 256 + t] = sigf(s);
        }
    }
    if (phase_mask == 7) cg::this_grid().sync();

    // ---------- phase 3: out = x * gate[bc], two channels interleaved ----------
    if (phase_mask & 4) {
        const float g0 = gates[bc];
        const float g1 = gates[bc + GRID];
        const f32x4* __restrict__ xi0 = (const f32x4*)x + (size_t)bc * CH_F4;
        const f32x4* __restrict__ xi1 = xi0 + (size_t)GRID * CH_F4;
        f32x4* __restrict__ oi0 = (f32x4*)out + (size_t)bc * CH_F4;
        f32x4* __restrict__ oi1 = oi0 + (size_t)GRID * CH_F4;
        for (int i = tid; i < CH_F4; i += 256) {
            f32x4 v0 = xi0[i];
            f32x4 v1 = xi1[i];
            v0 *= g0;
            v1 *= g1;
            __builtin_nontemporal_store(v0, &oi0[i]);
            __builtin_nontemporal_store(v1, &oi1[i]);
        }
    }
}

extern "C" void kernel_launch(void* const* d_in, const int* in_sizes, int n_in,
                              void* d_out, int out_size, void* d_ws, size_t ws_size,
                              hipStream_t stream) {
    const float* x      = (const float*)d_in[0];
    const float* W_ih   = (const float*)d_in[1];   // (128,1)
    const float* W_hh   = (const float*)d_in[2];   // (128,32)
    const float* b_ih   = (const float*)d_in[3];   // (128,)
    const float* b_hh   = (const float*)d_in[4];   // (128,)
    const float* gate_w = (const float*)d_in[5];   // (1,32)
    const float* gate_b = (const float*)d_in[6];   // (1,)
    float* out = (float*)d_out;
    float* ws  = (float*)d_ws;                     // 2048 floats used

    int mask_all = 7;
    void* args[] = {(void*)&x, (void*)&W_ih, (void*)&W_hh, (void*)&b_ih,
                    (void*)&b_hh, (void*)&gate_w, (void*)&gate_b,
                    (void*)&out, (void*)&ws, (void*)&mask_all};
    hipError_t err = hipLaunchCooperativeKernel((void*)fused_kernel,
                                                dim3(GRID), dim3(256),
                                                args, 0, stream);
    if (err != hipSuccess) {
        // Deterministic fallback: same kernel, three phase-masked plain
        // launches (grid.sync never executed when mask != 7).
        fused_kernel<<<GRID, 256, 0, stream>>>(x, W_ih, W_hh, b_ih, b_hh,
                                               gate_w, gate_b, out, ws, 1);
        fused_kernel<<<4, 256, 0, stream>>>(x, W_ih, W_hh, b_ih, b_hh,
                                            gate_w, gate_b, out, ws, 2);
        fused_kernel<<<GRID, 256, 0, stream>>>(x, W_ih, W_hh, b_ih, b_hh,
                                               gate_w, gate_b, out, ws, 4);
    }
}

// Round 7
// 409.327 us; speedup vs baseline: 1.2490x; 1.2490x over previous
//
#include <hip/hip_runtime.h>

// Problem: x (B=4, C=256, D=32, H=64, W=64) fp32.
// 1) reflect-pad(2) + per-(b,c) mean  == weighted sum over original x
// 2) LSTMCell scan over C=256 channels (B=4, hidden=32, input=1)
// 3) gate[b,c] = sigmoid(h_c . gate_w + gate_b);  out = x * gate[b,c]
//
// R6 counters: streams latency-bound (24% HBM @ 8 waves/CU), LSTM weight
// arrays spilled (VGPR=52 < 64 floats of weights). This round: 3 plain
// kernels, full-occupancy streams, macro-flattened register weights.

#define MEAN_DEN (1.0f / 166464.0f)   // 36*68*68

typedef unsigned int uint;
typedef float f32x4 __attribute__((ext_vector_type(4)));
typedef float f32x2 __attribute__((ext_vector_type(2)));

__device__ __forceinline__ float sigf(float x) {
    return 1.0f / (1.0f + __expf(-x));
}
__device__ __forceinline__ float tanh_fast(float x) {
    return fmaf(2.0f, sigf(2.0f * x), -1.0f);   // tanh(x) = 2*sigmoid(2x) - 1
}

// ---------- Kernel 1: weighted half-channel partial sums ----------
// 2048 blocks (8/CU -> 32 waves/CU, 100% occupancy). Block bid: channel
// bid>>1, half bid&1 (16384 float4 = 256KB contiguous). Raw weighted sum
// to part[bid]; scaling deferred to the LSTM prologue.
__global__ __launch_bounds__(256) void mean_kernel(const float* __restrict__ x,
                                                   float* __restrict__ part) {
    const int bid = blockIdx.x;
    const int ch = bid >> 1, half = bid & 1;
    const f32x4* __restrict__ p = (const f32x4*)x + (size_t)ch * 32768 + half * 16384;
    const int base = half * 16384;
    const int tid = threadIdx.x;

    float sum = 0.0f;
#pragma unroll 4
    for (int il = tid; il < 16384; il += 256) {
        f32x4 v = p[il];
        const int i = base + il;          // f4 index within the full channel
        const int q = i & 15;             // f4 index within W-row
        const int hh = (i >> 4) & 63;
        const int d = i >> 10;
        float t = (v.x + v.y) + (v.z + v.w);
        if (q == 0 || q == 15) t += v.y + v.z;   // W positions 1,2,61,62 doubled
        const float wd = ((d == 1) | (d == 2) | (d == 29) | (d == 30)) ? 2.0f : 1.0f;
        const float wh = ((hh == 1) | (hh == 2) | (hh == 61) | (hh == 62)) ? 2.0f : 1.0f;
        sum = fmaf(wd * wh, t, sum);
    }

    __shared__ float red[256];
    red[tid] = sum;
    __syncthreads();
    for (int s = 128; s > 0; s >>= 1) {
        if (tid < s) red[tid] += red[tid + s];
        __syncthreads();
    }
    if (tid == 0) part[bid] = red[0];
}

// ---------- Kernel 2: LSTM scan, 4 single-wave blocks ----------
// Lane l owns gate rows l and l+64 (l<32: i,g ; l>=32: f,o). h register-
// resident (lane k holds h_k); broadcast via v_readlane; i/f<->g/o via
// permlane32_swap. Weights are 64 NAMED scalars (macro-flattened) so the
// compiler cannot demote them to scratch (R6 showed VGPR=52 => arrays
// had spilled). Single-wave LDS needs no barriers.
#define RL(v, k) __builtin_bit_cast(float, \
    __builtin_amdgcn_readlane(__builtin_bit_cast(int, (v)), (k)))
#define DW(k) const float w0_##k = W_hh[r0 * 32 + (k)]; \
              const float w1_##k = W_hh[r1 * 32 + (k)];
#define GK(k) { const float hk = RL(h, k); \
                z0 = fmaf(hk, w0_##k, z0); z1 = fmaf(hk, w1_##k, z1); }

__global__ __launch_bounds__(64, 1) void lstm_kernel(
    const float* __restrict__ part,
    const float* __restrict__ W_ih, const float* __restrict__ W_hh,
    const float* __restrict__ b_ih, const float* __restrict__ b_hh,
    const float* __restrict__ gate_w, const float* __restrict__ gate_b,
    float* __restrict__ gates)
{
    __shared__ float cs[256];
    __shared__ float hist[257 * 33];     // stride-33: conflict-free epilogue reads

    const int b = blockIdx.x;            // batch 0..3
    const int l = threadIdx.x;           // lane 0..63
    const int r0 = l, r1 = l + 64;

    const float wih0 = W_ih[r0];
    const float wih1 = W_ih[r1];
    const float bias0 = b_ih[r0] + b_hh[r0];
    const float bias1 = b_ih[r1] + b_hh[r1];
    DW(0)  DW(1)  DW(2)  DW(3)  DW(4)  DW(5)  DW(6)  DW(7)
    DW(8)  DW(9)  DW(10) DW(11) DW(12) DW(13) DW(14) DW(15)
    DW(16) DW(17) DW(18) DW(19) DW(20) DW(21) DW(22) DW(23)
    DW(24) DW(25) DW(26) DW(27) DW(28) DW(29) DW(30) DW(31)

    // combine half-channel partials -> channel means for this batch
    const f32x2* __restrict__ p2 = (const f32x2*)part + b * 256;
#pragma unroll
    for (int j = 0; j < 4; j++) {
        const int cch = j * 64 + l;
        f32x2 pr = p2[cch];
        cs[cch] = (pr.x + pr.y) * MEAN_DEN;
    }

    float h = 0.0f, cstate = 0.0f;
    for (int t = 0; t < 256; t++) {
        const float inp = cs[t];
        float z0 = fmaf(inp, wih0, bias0);
        float z1 = fmaf(inp, wih1, bias1);
        GK(0)  GK(1)  GK(2)  GK(3)  GK(4)  GK(5)  GK(6)  GK(7)
        GK(8)  GK(9)  GK(10) GK(11) GK(12) GK(13) GK(14) GK(15)
        GK(16) GK(17) GK(18) GK(19) GK(20) GK(21) GK(22) GK(23)
        GK(24) GK(25) GK(26) GK(27) GK(28) GK(29) GK(30) GK(31)
        float zf, zo;
#if __has_builtin(__builtin_amdgcn_permlane32_swap)
        {
            auto ra = __builtin_amdgcn_permlane32_swap(
                __builtin_bit_cast(uint, z0), __builtin_bit_cast(uint, z0), false, false);
            auto rb = __builtin_amdgcn_permlane32_swap(
                __builtin_bit_cast(uint, z1), __builtin_bit_cast(uint, z1), false, false);
            zf = __builtin_bit_cast(float, ra[1]);
            zo = __builtin_bit_cast(float, rb[1]);
        }
#else
        zf = __shfl_xor(z0, 32);
        zo = __shfl_xor(z1, 32);
#endif
        // valid in lanes<32 only (high lanes compute finite garbage, never read)
        cstate = sigf(zf) * cstate + sigf(z0) * tanh_fast(z1);
        h = sigf(zo) * tanh_fast(cstate);
        if (l < 32) hist[(t + 1) * 33 + l] = h;   // off critical path
    }

    // deferred output gates: lane handles t = l, l+64, l+128, l+192
    const float gb = gate_b[0];
#pragma unroll
    for (int chunk = 0; chunk < 4; chunk++) {
        const int t = chunk * 64 + l;
        const float* hrow = &hist[(t + 1) * 33];
        float s = gb;
#pragma unroll
        for (int k = 0; k < 32; k++) s = fmaf(hrow[k], gate_w[k], s);
        gates[b * 256 + t] = sigf(s);
    }
}

// ---------- Kernel 3: out = x * gate[ch], half-channel per block ----------
// 2048 blocks (100% occupancy), reversed order: L3-warm tail of x (last
// channels read by mean_kernel) is re-read first. Nontemporal stores keep
// the write stream from evicting x.
__global__ __launch_bounds__(256) void scale_kernel(const float* __restrict__ x,
                                                    const float* __restrict__ gates,
                                                    float* __restrict__ out) {
    const int rb = 2047 - (int)blockIdx.x;
    const int ch = rb >> 1, half = rb & 1;
    const float g = gates[ch];
    const size_t off = (size_t)ch * 32768 + half * 16384;
    const f32x4* __restrict__ xi = (const f32x4*)x + off;
    f32x4* __restrict__ oi = (f32x4*)out + off;
#pragma unroll 4
    for (int i = threadIdx.x; i < 16384; i += 256) {
        f32x4 v = xi[i];
        v *= g;
        __builtin_nontemporal_store(v, &oi[i]);
    }
}

extern "C" void kernel_launch(void* const* d_in, const int* in_sizes, int n_in,
                              void* d_out, int out_size, void* d_ws, size_t ws_size,
                              hipStream_t stream) {
    const float* x      = (const float*)d_in[0];
    const float* W_ih   = (const float*)d_in[1];   // (128,1)
    const float* W_hh   = (const float*)d_in[2];   // (128,32)
    const float* b_ih   = (const float*)d_in[3];   // (128,)
    const float* b_hh   = (const float*)d_in[4];   // (128,)
    const float* gate_w = (const float*)d_in[5];   // (1,32)
    const float* gate_b = (const float*)d_in[6];   // (1,)
    float* out = (float*)d_out;

    float* part  = (float*)d_ws;          // 2048 floats: half-channel partials
    float* gates = (float*)d_ws + 2048;   // 1024 floats

    mean_kernel<<<2048, 256, 0, stream>>>(x, part);
    lstm_kernel<<<4, 64, 0, stream>>>(part, W_ih, W_hh, b_ih, b_hh,
                                      gate_w, gate_b, gates);
    scale_kernel<<<2048, 256, 0, stream>>>(x, gates, out);
}

// Round 8
// 378.450 us; speedup vs baseline: 1.3509x; 1.0816x over previous
//
#include <hip/hip_runtime.h>

// Problem: x (B=4, C=256, D=32, H=64, W=64) fp32.
// 1) reflect-pad(2) + per-(b,c) mean  == weighted sum over original x
// 2) LSTMCell scan over C=256 channels (B=4, hidden=32, input=1)
// 3) gate[b,c] = sigmoid(h_c . gate_w + gate_b);  out = x * gate[b,c]
//
// R7 budget: streams at only ~4.3 TB/s aggregate (65% of ceiling); LSTM ~25us.
// This round: deeper unroll (8 loads in flight/thread) on both streams,
// 4-way split accumulator chains in the LSTM.

#define MEAN_DEN (1.0f / 166464.0f)   // 36*68*68

typedef unsigned int uint;
typedef float f32x4 __attribute__((ext_vector_type(4)));
typedef float f32x2 __attribute__((ext_vector_type(2)));

__device__ __forceinline__ float sigf(float x) {
    return 1.0f / (1.0f + __expf(-x));
}
__device__ __forceinline__ float tanh_fast(float x) {
    return fmaf(2.0f, sigf(2.0f * x), -1.0f);   // tanh(x) = 2*sigmoid(2x) - 1
}

// ---------- Kernel 1: weighted half-channel partial sums ----------
// 2048 blocks (8/CU, 100% occupancy). Block bid: channel bid>>1, half bid&1
// (16384 f4 = 256KB contiguous). 8 independent loads in flight per thread.
__global__ __launch_bounds__(256) void mean_kernel(const float* __restrict__ x,
                                                   float* __restrict__ part) {
    const int bid = blockIdx.x;
    const int ch = bid >> 1, half = bid & 1;
    const f32x4* __restrict__ p = (const f32x4*)x + (size_t)ch * 32768 + half * 16384;
    const int base = half * 16384;
    const int tid = threadIdx.x;

    float s0 = 0.0f, s1 = 0.0f, s2 = 0.0f, s3 = 0.0f;
    // 64 strided iterations, 8 per unrolled group -> 8 loads issued back-to-back
#pragma unroll
    for (int g = 0; g < 8; g++) {
        f32x4 v[8];
#pragma unroll
        for (int u = 0; u < 8; u++) v[u] = p[g * 2048 + u * 256 + tid];
#pragma unroll
        for (int u = 0; u < 8; u++) {
            const int i = base + g * 2048 + u * 256 + tid;
            const int q = i & 15;             // f4 index within W-row
            const int hh = (i >> 4) & 63;
            const int d = i >> 10;
            float t = (v[u].x + v[u].y) + (v[u].z + v[u].w);
            if (q == 0 || q == 15) t += v[u].y + v[u].z;   // W 1,2,61,62 doubled
            const float wd = ((d == 1) | (d == 2) | (d == 29) | (d == 30)) ? 2.0f : 1.0f;
            const float wh = ((hh == 1) | (hh == 2) | (hh == 61) | (hh == 62)) ? 2.0f : 1.0f;
            float* acc = (u & 2) ? ((u & 1) ? &s3 : &s2) : ((u & 1) ? &s1 : &s0);
            *acc = fmaf(wd * wh, t, *acc);
        }
    }
    float sum = (s0 + s1) + (s2 + s3);

    __shared__ float red[256];
    red[tid] = sum;
    __syncthreads();
    for (int s = 128; s > 0; s >>= 1) {
        if (tid < s) red[tid] += red[tid + s];
        __syncthreads();
    }
    if (tid == 0) part[bid] = red[0];
}

// ---------- Kernel 2: LSTM scan, 4 single-wave blocks ----------
// Lane l owns gate rows l and l+64 (l<32: i,g ; l>=32: f,o). h register-
// resident; broadcast via v_readlane; i/f<->g/o via permlane32_swap.
// Weights are 64 NAMED scalars; z accumulation split 4-way for ILP.
#define RL(v, k) __builtin_bit_cast(float, \
    __builtin_amdgcn_readlane(__builtin_bit_cast(int, (v)), (k)))
#define DW(k) const float w0_##k = W_hh[r0 * 32 + (k)]; \
              const float w1_##k = W_hh[r1 * 32 + (k)];
#define GK(k, A0, A1) { const float hk = RL(h, k); \
                A0 = fmaf(hk, w0_##k, A0); A1 = fmaf(hk, w1_##k, A1); }

__global__ __launch_bounds__(64, 1) void lstm_kernel(
    const float* __restrict__ part,
    const float* __restrict__ W_ih, const float* __restrict__ W_hh,
    const float* __restrict__ b_ih, const float* __restrict__ b_hh,
    const float* __restrict__ gate_w, const float* __restrict__ gate_b,
    float* __restrict__ gates)
{
    __shared__ float cs[256];
    __shared__ float hist[257 * 33];     // stride-33: conflict-free epilogue reads

    const int b = blockIdx.x;            // batch 0..3
    const int l = threadIdx.x;           // lane 0..63
    const int r0 = l, r1 = l + 64;

    const float wih0 = W_ih[r0];
    const float wih1 = W_ih[r1];
    const float bias0 = b_ih[r0] + b_hh[r0];
    const float bias1 = b_ih[r1] + b_hh[r1];
    DW(0)  DW(1)  DW(2)  DW(3)  DW(4)  DW(5)  DW(6)  DW(7)
    DW(8)  DW(9)  DW(10) DW(11) DW(12) DW(13) DW(14) DW(15)
    DW(16) DW(17) DW(18) DW(19) DW(20) DW(21) DW(22) DW(23)
    DW(24) DW(25) DW(26) DW(27) DW(28) DW(29) DW(30) DW(31)

    // combine half-channel partials -> channel means for this batch
    const f32x2* __restrict__ p2 = (const f32x2*)part + b * 256;
#pragma unroll
    for (int j = 0; j < 4; j++) {
        const int cch = j * 64 + l;
        f32x2 pr = p2[cch];
        cs[cch] = (pr.x + pr.y) * MEAN_DEN;
    }

    float h = 0.0f, cstate = 0.0f;
    for (int t = 0; t < 256; t++) {
        const float inp = cs[t];
        // 4 independent accumulator pairs: dependent chain 8 deep, not 32
        float a0 = fmaf(inp, wih0, bias0), b0 = 0.f, c0 = 0.f, d0 = 0.f;
        float a1 = fmaf(inp, wih1, bias1), b1 = 0.f, c1 = 0.f, d1 = 0.f;
        GK(0,a0,a1)  GK(1,b0,b1)  GK(2,c0,c1)  GK(3,d0,d1)
        GK(4,a0,a1)  GK(5,b0,b1)  GK(6,c0,c1)  GK(7,d0,d1)
        GK(8,a0,a1)  GK(9,b0,b1)  GK(10,c0,c1) GK(11,d0,d1)
        GK(12,a0,a1) GK(13,b0,b1) GK(14,c0,c1) GK(15,d0,d1)
        GK(16,a0,a1) GK(17,b0,b1) GK(18,c0,c1) GK(19,d0,d1)
        GK(20,a0,a1) GK(21,b0,b1) GK(22,c0,c1) GK(23,d0,d1)
        GK(24,a0,a1) GK(25,b0,b1) GK(26,c0,c1) GK(27,d0,d1)
        GK(28,a0,a1) GK(29,b0,b1) GK(30,c0,c1) GK(31,d0,d1)
        const float z0 = (a0 + b0) + (c0 + d0);
        const float z1 = (a1 + b1) + (c1 + d1);
        float zf, zo;
#if __has_builtin(__builtin_amdgcn_permlane32_swap)
        {
            auto ra = __builtin_amdgcn_permlane32_swap(
                __builtin_bit_cast(uint, z0), __builtin_bit_cast(uint, z0), false, false);
            auto rb = __builtin_amdgcn_permlane32_swap(
                __builtin_bit_cast(uint, z1), __builtin_bit_cast(uint, z1), false, false);
            zf = __builtin_bit_cast(float, ra[1]);
            zo = __builtin_bit_cast(float, rb[1]);
        }
#else
        zf = __shfl_xor(z0, 32);
        zo = __shfl_xor(z1, 32);
#endif
        // valid in lanes<32 only (high lanes compute finite garbage, never read)
        cstate = sigf(zf) * cstate + sigf(z0) * tanh_fast(z1);
        h = sigf(zo) * tanh_fast(cstate);
        if (l < 32) hist[(t + 1) * 33 + l] = h;   // off critical path
    }

    // deferred output gates: lane handles t = l, l+64, l+128, l+192
    const float gb = gate_b[0];
#pragma unroll
    for (int chunk = 0; chunk < 4; chunk++) {
        const int t = chunk * 64 + l;
        const float* hrow = &hist[(t + 1) * 33];
        float s = gb;
#pragma unroll
        for (int k = 0; k < 32; k++) s = fmaf(hrow[k], gate_w[k], s);
        gates[b * 256 + t] = sigf(s);
    }
}

// ---------- Kernel 3: out = x * gate[ch] ----------
// 2048 blocks, 8 loads + 8 NT stores per scheduling window.
__global__ __launch_bounds__(256) void scale_kernel(const float* __restrict__ x,
                                                    const float* __restrict__ gates,
                                                    float* __restrict__ out) {
    const int bid = blockIdx.x;
    const int ch = bid >> 1, half = bid & 1;
    const float g = gates[ch];
    const size_t off = (size_t)ch * 32768 + half * 16384;
    const f32x4* __restrict__ xi = (const f32x4*)x + off;
    f32x4* __restrict__ oi = (f32x4*)out + off;
    const int tid = threadIdx.x;
#pragma unroll
    for (int gr = 0; gr < 8; gr++) {
        f32x4 v[8];
#pragma unroll
        for (int u = 0; u < 8; u++) v[u] = xi[gr * 2048 + u * 256 + tid];
#pragma unroll
        for (int u = 0; u < 8; u++) {
            v[u] *= g;
            __builtin_nontemporal_store(v[u], &oi[gr * 2048 + u * 256 + tid]);
        }
    }
}

extern "C" void kernel_launch(void* const* d_in, const int* in_sizes, int n_in,
                              void* d_out, int out_size, void* d_ws, size_t ws_size,
                              hipStream_t stream) {
    const float* x      = (const float*)d_in[0];
    const float* W_ih   = (const float*)d_in[1];   // (128,1)
    const float* W_hh   = (const float*)d_in[2];   // (128,32)
    const float* b_ih   = (const float*)d_in[3];   // (128,)
    const float* b_hh   = (const float*)d_in[4];   // (128,)
    const float* gate_w = (const float*)d_in[5];   // (1,32)
    const float* gate_b = (const float*)d_in[6];   // (1,)
    float* out = (float*)d_out;

    float* part  = (float*)d_ws;          // 2048 floats: half-channel partials
    float* gates = (float*)d_ws + 2048;   // 1024 floats

    mean_kernel<<<2048, 256, 0, stream>>>(x, part);
    lstm_kernel<<<4, 64, 0, stream>>>(part, W_ih, W_hh, b_ih, b_hh,
                                      gate_w, gate_b, gates);
    scale_kernel<<<2048, 256, 0, stream>>>(x, gates, out);
}